// Round 13
// baseline (240.538 us; speedup 1.0000x reference)
//
#include <hip/hip_runtime.h>
#include <math.h>

typedef float f32x4 __attribute__((ext_vector_type(4)));
typedef __bf16 bf16x8 __attribute__((ext_vector_type(8)));
typedef __bf16 bf16x4 __attribute__((ext_vector_type(4)));

#define MFMA16(a, b, c) __builtin_amdgcn_mfma_f32_16x16x32_bf16((a), (b), (c), 0, 0, 0)

constexpr int Bsz = 2, Nseq = 2048, Dm = 1024, Hh = 16, HDim = 64, F3 = 192;
constexpr int Mrows = Bsz * Nseq;   // 4096
constexpr int NC = Hh * F3;         // 3072 output cols
constexpr float QSCALE = 0.125f * 1.4426950408889634f;

__device__ inline void load_lds16(const void* g, void* l) {
    __builtin_amdgcn_global_load_lds((const __attribute__((address_space(1))) void*)g,
                                     (__attribute__((address_space(3))) void*)l, 16, 0, 0);
}

#define FENCE asm volatile("" ::: "memory")
#define BARRIER do { FENCE; __builtin_amdgcn_s_barrier(); FENCE; } while (0)

// V key permutation within each 64-block (pi'): for key = 16g + quad*4 + r,
// pos = (g>>1)*32 + quad*8 + (g&1)*4 + r
//     = ((n>>5)&1)<<5 | (n&12)<<1 | ((n>>4)&1)<<2 | (n&3)   [bijective]
// Chosen so the attn PV A-fragment (slot j=(g&1)*4+r of fragment g>>1) is a pure
// in-lane packing of the swapped-QK^T outputs. Note pos[1:0] = key&3 = rg, so the
// 4 rg values of a gemm acc register are CONTIGUOUS in vt -> bf16x4 packed stores.

// ---------------- kernel 0: fused x fp32->bf16 AND W transpose (1 launch) -------
__global__ __launch_bounds__(256) void conv_xw_kernel(const float* __restrict__ x,
                                                      __bf16* __restrict__ xb,
                                                      const float* __restrict__ w,
                                                      __bf16* __restrict__ wt) {
    __shared__ __bf16 tile[32][66];
    if (blockIdx.x < 2048) {
        int i = blockIdx.x * 256 + threadIdx.x;
        const float4* xv = reinterpret_cast<const float4*>(x);
        float4 a = xv[2 * i];
        float4 b = xv[2 * i + 1];
        bf16x8 o = {(__bf16)a.x, (__bf16)a.y, (__bf16)a.z, (__bf16)a.w,
                    (__bf16)b.x, (__bf16)b.y, (__bf16)b.z, (__bf16)b.w};
        *reinterpret_cast<bf16x8*>(xb + 8 * i) = o;
    } else {
        int id = blockIdx.x - 2048;              // 0..1535
        int h = id / 96, rem = id % 96;
        int d0 = (rem & 31) * 32, c0 = (rem >> 5) * 64;
        for (int i = threadIdx.x; i < 32 * 64; i += 256) {
            int di = i >> 6, cj = i & 63;
            tile[di][cj] = (__bf16)w[(size_t)(h * Dm + d0 + di) * F3 + c0 + cj];
        }
        __syncthreads();
        for (int i = threadIdx.x; i < 32 * 64; i += 256) {
            int ci = i >> 5, dj = i & 31;
            wt[(size_t)(h * F3 + c0 + ci) * Dm + d0 + dj] = tile[dj][ci];
        }
    }
}

// ---------------- kernel 1: W transpose alone (fallback path only) ----------------
__global__ __launch_bounds__(256) void conv_w_kernel(const float* __restrict__ w,
                                                     __bf16* __restrict__ wt) {
    __shared__ __bf16 tile[32][66];
    int h = blockIdx.z, d0 = blockIdx.x * 32, c0 = blockIdx.y * 64;
    for (int i = threadIdx.x; i < 32 * 64; i += 256) {
        int di = i >> 6, cj = i & 63;
        tile[di][cj] = (__bf16)w[(size_t)(h * Dm + d0 + di) * F3 + c0 + cj];
    }
    __syncthreads();
    for (int i = threadIdx.x; i < 32 * 64; i += 256) {
        int ci = i >> 5, dj = i & 31;
        wt[(size_t)(h * F3 + c0 + ci) * Dm + d0 + dj] = tile[dj][ci];
    }
}

// ---------------- kernel 2a: proj as 128x192 GEMM, 2 blocks/CU ----------------
// Change vs R12: vt stores packed as bf16x4 (pi' makes rg contiguous): 16 scalar
// 2B stores -> 4x 8B stores per thread on the V path. Schedule/staging unchanged.
__global__ __launch_bounds__(512, 4) void gemm_proj(const __bf16* __restrict__ xb,
                                                    const __bf16* __restrict__ wt,
                                                    const float* __restrict__ bias,
                                                    __bf16* __restrict__ kbuf,
                                                    __bf16* __restrict__ qbuf,
                                                    __bf16* __restrict__ vt) {
    __shared__ __align__(16) __bf16 Ab[2][128 * 64];
    __shared__ __align__(16) __bf16 Bb[2][192 * 64];

    int flat = blockIdx.x;                       // 0..511
    int swz = (flat & 7) * 64 + (flat >> 3);     // bijective XCD swizzle (512 = 8*64)
    int bm = swz >> 4, bn = swz & 15;            // 32 x 16 tile grid
    int r0 = bm * 128, n0 = bn * 192;

    int w = threadIdx.x >> 6, lane = threadIdx.x & 63;
    int col = lane & 15, quad = lane >> 4;
    int wm = w >> 2, wn = w & 3;                 // per-wave output 64 x 48

    f32x4 acc[4][3] = {};

    int rl = lane >> 3;
    int cg = ((lane & 7) ^ rl) * 8;              // pre-swizzled source chunk

    auto stage = [&](int t, int s) {
#pragma unroll
        for (int i = 0; i < 2; i++) {
            int rowb = w * 16 + i * 8;           // multiple of 8
            load_lds16(xb + (size_t)(r0 + rowb + rl) * Dm + t * 64 + cg,
                       &Ab[s][rowb * 64]);
        }
#pragma unroll
        for (int i = 0; i < 3; i++) {
            int rowb = w * 24 + i * 8;           // multiple of 8
            load_lds16(wt + (size_t)(n0 + rowb + rl) * Dm + t * 64 + cg,
                       &Bb[s][rowb * 64]);
        }
    };

    stage(0, 0);
    stage(1, 1);

    for (int j = 0; j < 16; j++) {
        int s = j & 1;
        if (j < 15) asm volatile("s_waitcnt vmcnt(5)" ::: "memory");
        else        asm volatile("s_waitcnt vmcnt(0)" ::: "memory");
        BARRIER;

#pragma unroll
        for (int ks = 0; ks < 2; ks++) {
            int cq = ks * 4 + quad;
            bf16x8 af[4], bfr[3];
#pragma unroll
            for (int mt = 0; mt < 4; mt++) {
                int row = wm * 64 + mt * 16 + col;
                af[mt] = *reinterpret_cast<const bf16x8*>(
                    &Ab[s][row * 64 + ((cq ^ (row & 7)) * 8)]);
            }
#pragma unroll
            for (int nt = 0; nt < 3; nt++) {
                int row = wn * 48 + nt * 16 + col;
                bfr[nt] = *reinterpret_cast<const bf16x8*>(
                    &Bb[s][row * 64 + ((cq ^ (row & 7)) * 8)]);
            }
            __builtin_amdgcn_s_setprio(1);
#pragma unroll
            for (int mt = 0; mt < 4; mt++)
#pragma unroll
                for (int nt = 0; nt < 3; nt++)
                    acc[mt][nt] = MFMA16(af[mt], bfr[nt], acc[mt][nt]);
            __builtin_amdgcn_s_setprio(0);
        }

        BARRIER;
        if (j + 2 < 16) stage(j + 2, s);
    }

#pragma unroll
    for (int nt = 0; nt < 3; nt++) {
        int g = n0 + wn * 48 + nt * 16 + col;
        int h = g / F3, c = g - h * F3;
        float bv = bias[g];
        bool isq = (c >= 64 && c < 128), isv = (c >= 128);
        int cd = c & 63;
#pragma unroll
        for (int mt = 0; mt < 4; mt++) {
            int rbase = r0 + wm * 64 + mt * 16 + quad * 4;   // rg=0 row
            int b = rbase >> 11, n = rbase & (Nseq - 1);
            size_t bh = (size_t)(b * Hh + h);
            if (isv) {
                // pi'(n) for rg=0..3 is contiguous: pack one bf16x4 store
                int npb = (n & ~63) | (((n >> 5) & 1) << 5) | ((n & 12) << 1)
                        | (((n >> 4) & 1) << 2);
                bf16x4 pv;
#pragma unroll
                for (int rg = 0; rg < 4; rg++) pv[rg] = (__bf16)(acc[mt][nt][rg] + bv);
                *reinterpret_cast<bf16x4*>(&vt[(bh * HDim + cd) * Nseq + npb]) = pv;
            } else {
                __bf16* dst = (isq) ? qbuf : kbuf;
#pragma unroll
                for (int rg = 0; rg < 4; rg++) {
                    float v = acc[mt][nt][rg] + bv;
                    if (isq) v *= QSCALE;
                    dst[(bh * Nseq + n + rg) * HDim + cd] = (__bf16)v;
                }
            }
        }
    }
}

// ---------------- kernel 2b: fallback proj if ws too small ----------------
__global__ __launch_bounds__(256) void proj_small(const float* __restrict__ x,
                                                  const __bf16* __restrict__ wt,
                                                  const float* __restrict__ bias,
                                                  __bf16* __restrict__ kbuf,
                                                  __bf16* __restrict__ qbuf,
                                                  __bf16* __restrict__ vt) {
    int h = blockIdx.y;
    int wave = threadIdx.x >> 6, lane = threadIdx.x & 63;
    int col = lane & 15, quad = lane >> 4;
    int r0 = blockIdx.x * 128 + wave * 32;

    f32x4 acc[12][2] = {};
    const float* xr0 = x + (size_t)(r0 + col) * Dm + quad * 8;
    const float* xr1 = xr0 + 16 * Dm;
    const __bf16* wbase = wt + (size_t)(h * F3 + col) * Dm + quad * 8;

    for (int k0 = 0; k0 < Dm; k0 += 32) {
        float4 a0lo = *reinterpret_cast<const float4*>(xr0 + k0);
        float4 a0hi = *reinterpret_cast<const float4*>(xr0 + k0 + 4);
        float4 a1lo = *reinterpret_cast<const float4*>(xr1 + k0);
        float4 a1hi = *reinterpret_cast<const float4*>(xr1 + k0 + 4);
        bf16x8 a0 = {(__bf16)a0lo.x, (__bf16)a0lo.y, (__bf16)a0lo.z, (__bf16)a0lo.w,
                     (__bf16)a0hi.x, (__bf16)a0hi.y, (__bf16)a0hi.z, (__bf16)a0hi.w};
        bf16x8 a1 = {(__bf16)a1lo.x, (__bf16)a1lo.y, (__bf16)a1lo.z, (__bf16)a1lo.w,
                     (__bf16)a1hi.x, (__bf16)a1hi.y, (__bf16)a1hi.z, (__bf16)a1hi.w};
#pragma unroll
        for (int ct = 0; ct < 12; ct++) {
            bf16x8 bf = *reinterpret_cast<const bf16x8*>(wbase + ct * 16 * Dm + k0);
            acc[ct][0] = MFMA16(a0, bf, acc[ct][0]);
            acc[ct][1] = MFMA16(a1, bf, acc[ct][1]);
        }
    }
#pragma unroll
    for (int ct = 0; ct < 12; ct++) {
        int c = ct * 16 + col;
        float bv = bias[h * F3 + c];
        int cd = c & 63;
        bool isq = (c >= 64 && c < 128), isv = (c >= 128);
#pragma unroll
        for (int rt = 0; rt < 2; rt++) {
#pragma unroll
            for (int rg = 0; rg < 4; rg++) {
                int r = r0 + rt * 16 + quad * 4 + rg;
                int b = r >> 11, n = r & (Nseq - 1);
                float v = acc[ct][rt][rg] + bv;
                if (isq) v *= QSCALE;
                size_t bh = (size_t)(b * Hh + h);
                if (isv) {
                    int np = (n & ~63) | (((n >> 5) & 1) << 5) | ((n & 12) << 1)
                           | (((n >> 4) & 1) << 2) | (n & 3);   // pi'(key)
                    vt[(bh * HDim + cd) * Nseq + np] = (__bf16)v;
                } else {
                    ((isq) ? qbuf : kbuf)[(bh * Nseq + n) * HDim + cd] = (__bf16)v;
                }
            }
        }
    }
}

// ---------------- kernel 3: flash attention, single-buffer max occupancy ------------
// Change vs R12: drop the K/V double buffer. LDS 32768 -> 16384 B => blocks/CU
// rises 5 -> 8 (wave-cap: 32 waves/CU = maximum occupancy; VGPR ~52 <= 64 so
// __launch_bounds__(256,8) holds). Cost: 2 barriers/iter + exposed staging
// latency per block -- absorbed by 8-way block interleave (the co-residency
// mechanism that delivered R8's and R10's wins). No prefetch => no tail reads.
// Schedule per iter: BARRIER (prev reads done) -> stage -> vmcnt(0) -> BARRIER
// (all waves' slices drained => tile visible) -> compute.
__global__ __launch_bounds__(256, 8) void attn_kernel(const __bf16* __restrict__ qbuf,
                                                      const __bf16* __restrict__ kbuf,
                                                      const __bf16* __restrict__ vt,
                                                      float* __restrict__ out) {
    __shared__ __align__(16) __bf16 Kb[64 * 64];    // [key][dim], swizzled chunks
    __shared__ __align__(16) __bf16 Vb[64 * 64];    // [dim][pos], swizzled chunks
    int bh = blockIdx.x;
    int b = bh >> 4, h = bh & 15;
    int tile = 31 - blockIdx.y;                 // heavy-first (LPT)
    int wave = threadIdx.x >> 6, lane = threadIdx.x & 63;
    int col = lane & 15, quad = lane >> 4;
    int q0 = tile * 64 + wave * 16;

    const __bf16* qbase = qbuf + (size_t)bh * Nseq * HDim;
    const __bf16* kbase = kbuf + (size_t)bh * Nseq * HDim;
    const __bf16* vbase = vt + (size_t)bh * HDim * Nseq;

    bf16x8 aq0 = *reinterpret_cast<const bf16x8*>(qbase + (q0 + col) * HDim + quad * 8);
    bf16x8 aq1 = *reinterpret_cast<const bf16x8*>(qbase + (q0 + col) * HDim + quad * 8 + 32);

    const bf16x8 vone = {(__bf16)1.f, (__bf16)1.f, (__bf16)1.f, (__bf16)1.f,
                         (__bf16)1.f, (__bf16)1.f, (__bf16)1.f, (__bf16)1.f};

    f32x4 o[4] = {};
    f32x4 ls = {};                       // per-row denominator accumulator

    int mb = tile * 64;                 // the one masked 64-key block (last iteration)
    int loop_end = mb + 64;
    int qi = q0 + col;                  // this lane's q-row (swapped layout)

    // staging indices: 4 waves x 2 instrs cover 64 rows; 16B chunk per lane
    int rl = lane >> 3;
    int srow0 = wave * 16 + rl;                       // instr 0 rows
    int srow1 = wave * 16 + 8 + rl;                   // instr 1 rows (same row&7 = rl)
    int sc = (lane & 7) ^ rl;                         // swizzled 16B chunk
    const __bf16* ksrc0 = kbase + srow0 * HDim + sc * 8;
    const __bf16* ksrc1 = kbase + srow1 * HDim + sc * 8;
    const __bf16* vsrc0 = vbase + (size_t)srow0 * Nseq + sc * 8;
    const __bf16* vsrc1 = vbase + (size_t)srow1 * Nseq + sc * 8;
    int d0 = wave * 1024, d1 = wave * 1024 + 512;     // wave-uniform LDS dests

    // readback swizzle offsets (K/V tiles)
    int sw0 = ((quad ^ (col & 7)) * 8);
    int sw1 = (((quad + 4) ^ (col & 7)) * 8);

    for (int kb = 0; kb < loop_end; kb += 64) {
        BARRIER;                                          // prev iter's reads complete
        load_lds16(ksrc0 + kb * HDim, &Kb[d0]);
        load_lds16(ksrc1 + kb * HDim, &Kb[d1]);
        load_lds16(vsrc0 + kb, &Vb[d0]);
        load_lds16(vsrc1 + kb, &Vb[d1]);
        asm volatile("s_waitcnt vmcnt(0)" ::: "memory");  // my slices landed
        BARRIER;                                          // tile visible to all waves

        bool masked = (kb == mb);
        // swapped QK^T: S^T = K x Q^T -> lane: q = col, key = quad*4+r (+16g)
        f32x4 z = {};
        f32x4 sc4[4];
#pragma unroll
        for (int g = 0; g < 4; g++) {
            const __bf16* krow = Kb + (col + 16 * g) * 64;
            bf16x8 k0 = *reinterpret_cast<const bf16x8*>(krow + sw0);
            bf16x8 k1 = *reinterpret_cast<const bf16x8*>(krow + sw1);
            sc4[g] = MFMA16(k0, aq0, z);
            sc4[g] = MFMA16(k1, aq1, sc4[g]);
        }
        // softmax (no-max): pack P directly into PV A-fragments.
        bf16x8 pa0, pa1;
        if (masked) {
#pragma unroll
            for (int g = 0; g < 4; g++)
#pragma unroll
                for (int r = 0; r < 4; r++) {
                    int key = kb + 16 * g + quad * 4 + r;
                    float p = (key <= qi) ? exp2f(sc4[g][r]) : 0.f;
                    if (g < 2) pa0[(g & 1) * 4 + r] = (__bf16)p;
                    else       pa1[(g & 1) * 4 + r] = (__bf16)p;
                }
        } else {
#pragma unroll
            for (int g = 0; g < 4; g++)
#pragma unroll
                for (int r = 0; r < 4; r++) {
                    float p = exp2f(sc4[g][r]);
                    if (g < 2) pa0[(g & 1) * 4 + r] = (__bf16)p;
                    else       pa1[(g & 1) * 4 + r] = (__bf16)p;
                }
        }
        // denominator: ones-MFMA row-sum (accumulates across blocks)
        ls = MFMA16(pa0, vone, ls);
        ls = MFMA16(pa1, vone, ls);
        // PV from LDS V tile (position space)
#pragma unroll
        for (int nt = 0; nt < 4; nt++) {
            const __bf16* vrow = Vb + (col + 16 * nt) * 64;
            bf16x8 v0 = *reinterpret_cast<const bf16x8*>(vrow + sw0);
            bf16x8 v1 = *reinterpret_cast<const bf16x8*>(vrow + sw1);
            o[nt] = MFMA16(pa0, v0, o[nt]);
            o[nt] = MFMA16(pa1, v1, o[nt]);
        }
    }

    float linv[4];
#pragma unroll
    for (int r = 0; r < 4; r++) linv[r] = 1.f / ls[r];
#pragma unroll
    for (int nt = 0; nt < 4; nt++) {
#pragma unroll
        for (int r = 0; r < 4; r++) {
            int qr = q0 + quad * 4 + r;
            out[((size_t)(b * Nseq + qr)) * Dm + h * HDim + nt * 16 + col] = o[nt][r] * linv[r];
        }
    }
}

extern "C" void kernel_launch(void* const* d_in, const int* in_sizes, int n_in,
                              void* d_out, int out_size, void* d_ws, size_t ws_size,
                              hipStream_t stream) {
    const float* x = nullptr;
    const float* w = nullptr;
    const float* bias = nullptr;
    for (int i = 0; i < n_in; i++) {
        if (in_sizes[i] == Mrows * Dm) x = (const float*)d_in[i];
        else if (in_sizes[i] == Hh * Dm * F3) w = (const float*)d_in[i];
        else if (in_sizes[i] == Hh * F3) bias = (const float*)d_in[i];
    }
    float* outp = (float*)d_out;

    // ws: wt 6 MB | kbuf 8 | qbuf 8 | vt 8 | xb 8 -> 38 MB
    char* ws = (char*)d_ws;
    __bf16* wt = (__bf16*)(ws);
    __bf16* kbuf = (__bf16*)(ws + 6291456);
    __bf16* qbuf = (__bf16*)(ws + 6291456 + 8388608);
    __bf16* vt = (__bf16*)(ws + 6291456 + 2 * 8388608);
    __bf16* xb = (__bf16*)(ws + 6291456 + 3 * 8388608);

    if (ws_size >= (size_t)(6291456 + 4 * 8388608)) {
        conv_xw_kernel<<<3584, 256, 0, stream>>>(x, xb, w, wt);
        gemm_proj<<<dim3((Mrows / 128) * (NC / 192)), 512, 0, stream>>>(xb, wt, bias, kbuf, qbuf, vt);
    } else {
        conv_w_kernel<<<dim3(Dm / 32, F3 / 64, Hh), 256, 0, stream>>>(w, wt);
        proj_small<<<dim3(Mrows / 128, Hh), 256, 0, stream>>>(x, wt, bias, kbuf, qbuf, vt);
    }
    attn_kernel<<<dim3(32, 32), 256, 0, stream>>>(qbuf, kbuf, vt, outp);
}

// Round 14
// 139.426 us; speedup vs baseline: 1.7252x; 1.7252x over previous
//
#include <hip/hip_runtime.h>
#include <math.h>

typedef float f32x4 __attribute__((ext_vector_type(4)));
typedef __bf16 bf16x8 __attribute__((ext_vector_type(8)));
typedef __bf16 bf16x4 __attribute__((ext_vector_type(4)));

#define MFMA16(a, b, c) __builtin_amdgcn_mfma_f32_16x16x32_bf16((a), (b), (c), 0, 0, 0)

constexpr int Bsz = 2, Nseq = 2048, Dm = 1024, Hh = 16, HDim = 64, F3 = 192;
constexpr int Mrows = Bsz * Nseq;   // 4096
constexpr int NC = Hh * F3;         // 3072 output cols
constexpr float QSCALE = 0.125f * 1.4426950408889634f;

__device__ inline void load_lds16(const void* g, void* l) {
    __builtin_amdgcn_global_load_lds((const __attribute__((address_space(1))) void*)g,
                                     (__attribute__((address_space(3))) void*)l, 16, 0, 0);
}

#define FENCE asm volatile("" ::: "memory")
#define BARRIER do { FENCE; __builtin_amdgcn_s_barrier(); FENCE; } while (0)

// V key permutation within each 64-block (pi'): for key = 16g + quad*4 + r,
// pos = (g>>1)*32 + quad*8 + (g&1)*4 + r
//     = ((n>>5)&1)<<5 | (n&12)<<1 | ((n>>4)&1)<<2 | (n&3)   [bijective]
// Chosen so the attn PV A-fragment (slot j=(g&1)*4+r of fragment g>>1) is a pure
// in-lane packing of the swapped-QK^T outputs. Note pos[1:0] = key&3 = rg, so the
// 4 rg values of a gemm acc register are CONTIGUOUS in vt -> bf16x4 packed stores.
//
// R13 lesson (reverted here): __launch_bounds__(256,8) on attn forced VGPR 32 ->
// scratch spills (WRITE_SIZE 16->250 MB). Occupancy must be bought with LDS, not
// register starvation.

// ---------------- kernel 0: fused x fp32->bf16 AND W transpose (1 launch) -------
__global__ __launch_bounds__(256) void conv_xw_kernel(const float* __restrict__ x,
                                                      __bf16* __restrict__ xb,
                                                      const float* __restrict__ w,
                                                      __bf16* __restrict__ wt) {
    __shared__ __bf16 tile[32][66];
    if (blockIdx.x < 2048) {
        int i = blockIdx.x * 256 + threadIdx.x;
        const float4* xv = reinterpret_cast<const float4*>(x);
        float4 a = xv[2 * i];
        float4 b = xv[2 * i + 1];
        bf16x8 o = {(__bf16)a.x, (__bf16)a.y, (__bf16)a.z, (__bf16)a.w,
                    (__bf16)b.x, (__bf16)b.y, (__bf16)b.z, (__bf16)b.w};
        *reinterpret_cast<bf16x8*>(xb + 8 * i) = o;
    } else {
        int id = blockIdx.x - 2048;              // 0..1535
        int h = id / 96, rem = id % 96;
        int d0 = (rem & 31) * 32, c0 = (rem >> 5) * 64;
        for (int i = threadIdx.x; i < 32 * 64; i += 256) {
            int di = i >> 6, cj = i & 63;
            tile[di][cj] = (__bf16)w[(size_t)(h * Dm + d0 + di) * F3 + c0 + cj];
        }
        __syncthreads();
        for (int i = threadIdx.x; i < 32 * 64; i += 256) {
            int ci = i >> 5, dj = i & 31;
            wt[(size_t)(h * F3 + c0 + ci) * Dm + d0 + dj] = tile[dj][ci];
        }
    }
}

// ---------------- kernel 1: W transpose alone (fallback path only) ----------------
__global__ __launch_bounds__(256) void conv_w_kernel(const float* __restrict__ w,
                                                     __bf16* __restrict__ wt) {
    __shared__ __bf16 tile[32][66];
    int h = blockIdx.z, d0 = blockIdx.x * 32, c0 = blockIdx.y * 64;
    for (int i = threadIdx.x; i < 32 * 64; i += 256) {
        int di = i >> 6, cj = i & 63;
        tile[di][cj] = (__bf16)w[(size_t)(h * Dm + d0 + di) * F3 + c0 + cj];
    }
    __syncthreads();
    for (int i = threadIdx.x; i < 32 * 64; i += 256) {
        int ci = i >> 5, dj = i & 31;
        wt[(size_t)(h * F3 + c0 + ci) * Dm + d0 + dj] = tile[dj][ci];
    }
}

// ---------------- kernel 2a: proj as 128x192 GEMM, 2 blocks/CU ----------------
// vt stores packed as bf16x4 (pi' makes rg contiguous) -- validated correct in R13.
__global__ __launch_bounds__(512, 4) void gemm_proj(const __bf16* __restrict__ xb,
                                                    const __bf16* __restrict__ wt,
                                                    const float* __restrict__ bias,
                                                    __bf16* __restrict__ kbuf,
                                                    __bf16* __restrict__ qbuf,
                                                    __bf16* __restrict__ vt) {
    __shared__ __align__(16) __bf16 Ab[2][128 * 64];
    __shared__ __align__(16) __bf16 Bb[2][192 * 64];

    int flat = blockIdx.x;                       // 0..511
    int swz = (flat & 7) * 64 + (flat >> 3);     // bijective XCD swizzle (512 = 8*64)
    int bm = swz >> 4, bn = swz & 15;            // 32 x 16 tile grid
    int r0 = bm * 128, n0 = bn * 192;

    int w = threadIdx.x >> 6, lane = threadIdx.x & 63;
    int col = lane & 15, quad = lane >> 4;
    int wm = w >> 2, wn = w & 3;                 // per-wave output 64 x 48

    f32x4 acc[4][3] = {};

    int rl = lane >> 3;
    int cg = ((lane & 7) ^ rl) * 8;              // pre-swizzled source chunk

    auto stage = [&](int t, int s) {
#pragma unroll
        for (int i = 0; i < 2; i++) {
            int rowb = w * 16 + i * 8;           // multiple of 8
            load_lds16(xb + (size_t)(r0 + rowb + rl) * Dm + t * 64 + cg,
                       &Ab[s][rowb * 64]);
        }
#pragma unroll
        for (int i = 0; i < 3; i++) {
            int rowb = w * 24 + i * 8;           // multiple of 8
            load_lds16(wt + (size_t)(n0 + rowb + rl) * Dm + t * 64 + cg,
                       &Bb[s][rowb * 64]);
        }
    };

    stage(0, 0);
    stage(1, 1);

    for (int j = 0; j < 16; j++) {
        int s = j & 1;
        if (j < 15) asm volatile("s_waitcnt vmcnt(5)" ::: "memory");
        else        asm volatile("s_waitcnt vmcnt(0)" ::: "memory");
        BARRIER;

#pragma unroll
        for (int ks = 0; ks < 2; ks++) {
            int cq = ks * 4 + quad;
            bf16x8 af[4], bfr[3];
#pragma unroll
            for (int mt = 0; mt < 4; mt++) {
                int row = wm * 64 + mt * 16 + col;
                af[mt] = *reinterpret_cast<const bf16x8*>(
                    &Ab[s][row * 64 + ((cq ^ (row & 7)) * 8)]);
            }
#pragma unroll
            for (int nt = 0; nt < 3; nt++) {
                int row = wn * 48 + nt * 16 + col;
                bfr[nt] = *reinterpret_cast<const bf16x8*>(
                    &Bb[s][row * 64 + ((cq ^ (row & 7)) * 8)]);
            }
            __builtin_amdgcn_s_setprio(1);
#pragma unroll
            for (int mt = 0; mt < 4; mt++)
#pragma unroll
                for (int nt = 0; nt < 3; nt++)
                    acc[mt][nt] = MFMA16(af[mt], bfr[nt], acc[mt][nt]);
            __builtin_amdgcn_s_setprio(0);
        }

        BARRIER;
        if (j + 2 < 16) stage(j + 2, s);
    }

#pragma unroll
    for (int nt = 0; nt < 3; nt++) {
        int g = n0 + wn * 48 + nt * 16 + col;
        int h = g / F3, c = g - h * F3;
        float bv = bias[g];
        bool isq = (c >= 64 && c < 128), isv = (c >= 128);
        int cd = c & 63;
#pragma unroll
        for (int mt = 0; mt < 4; mt++) {
            int rbase = r0 + wm * 64 + mt * 16 + quad * 4;   // rg=0 row
            int b = rbase >> 11, n = rbase & (Nseq - 1);
            size_t bh = (size_t)(b * Hh + h);
            if (isv) {
                // pi'(n) for rg=0..3 is contiguous: pack one bf16x4 store
                int npb = (n & ~63) | (((n >> 5) & 1) << 5) | ((n & 12) << 1)
                        | (((n >> 4) & 1) << 2);
                bf16x4 pv;
#pragma unroll
                for (int rg = 0; rg < 4; rg++) pv[rg] = (__bf16)(acc[mt][nt][rg] + bv);
                *reinterpret_cast<bf16x4*>(&vt[(bh * HDim + cd) * Nseq + npb]) = pv;
            } else {
                __bf16* dst = (isq) ? qbuf : kbuf;
#pragma unroll
                for (int rg = 0; rg < 4; rg++) {
                    float v = acc[mt][nt][rg] + bv;
                    if (isq) v *= QSCALE;
                    dst[(bh * Nseq + n + rg) * HDim + cd] = (__bf16)v;
                }
            }
        }
    }
}

// ---------------- kernel 2b: fallback proj if ws too small ----------------
__global__ __launch_bounds__(256) void proj_small(const float* __restrict__ x,
                                                  const __bf16* __restrict__ wt,
                                                  const float* __restrict__ bias,
                                                  __bf16* __restrict__ kbuf,
                                                  __bf16* __restrict__ qbuf,
                                                  __bf16* __restrict__ vt) {
    int h = blockIdx.y;
    int wave = threadIdx.x >> 6, lane = threadIdx.x & 63;
    int col = lane & 15, quad = lane >> 4;
    int r0 = blockIdx.x * 128 + wave * 32;

    f32x4 acc[12][2] = {};
    const float* xr0 = x + (size_t)(r0 + col) * Dm + quad * 8;
    const float* xr1 = xr0 + 16 * Dm;
    const __bf16* wbase = wt + (size_t)(h * F3 + col) * Dm + quad * 8;

    for (int k0 = 0; k0 < Dm; k0 += 32) {
        float4 a0lo = *reinterpret_cast<const float4*>(xr0 + k0);
        float4 a0hi = *reinterpret_cast<const float4*>(xr0 + k0 + 4);
        float4 a1lo = *reinterpret_cast<const float4*>(xr1 + k0);
        float4 a1hi = *reinterpret_cast<const float4*>(xr1 + k0 + 4);
        bf16x8 a0 = {(__bf16)a0lo.x, (__bf16)a0lo.y, (__bf16)a0lo.z, (__bf16)a0lo.w,
                     (__bf16)a0hi.x, (__bf16)a0hi.y, (__bf16)a0hi.z, (__bf16)a0hi.w};
        bf16x8 a1 = {(__bf16)a1lo.x, (__bf16)a1lo.y, (__bf16)a1lo.z, (__bf16)a1lo.w,
                     (__bf16)a1hi.x, (__bf16)a1hi.y, (__bf16)a1hi.z, (__bf16)a1hi.w};
#pragma unroll
        for (int ct = 0; ct < 12; ct++) {
            bf16x8 bf = *reinterpret_cast<const bf16x8*>(wbase + ct * 16 * Dm + k0);
            acc[ct][0] = MFMA16(a0, bf, acc[ct][0]);
            acc[ct][1] = MFMA16(a1, bf, acc[ct][1]);
        }
    }
#pragma unroll
    for (int ct = 0; ct < 12; ct++) {
        int c = ct * 16 + col;
        float bv = bias[h * F3 + c];
        int cd = c & 63;
        bool isq = (c >= 64 && c < 128), isv = (c >= 128);
#pragma unroll
        for (int rt = 0; rt < 2; rt++) {
#pragma unroll
            for (int rg = 0; rg < 4; rg++) {
                int r = r0 + rt * 16 + quad * 4 + rg;
                int b = r >> 11, n = r & (Nseq - 1);
                float v = acc[ct][rt][rg] + bv;
                if (isq) v *= QSCALE;
                size_t bh = (size_t)(b * Hh + h);
                if (isv) {
                    int np = (n & ~63) | (((n >> 5) & 1) << 5) | ((n & 12) << 1)
                           | (((n >> 4) & 1) << 2) | (n & 3);   // pi'(key)
                    vt[(bh * HDim + cd) * Nseq + np] = (__bf16)v;
                } else {
                    ((isq) ? qbuf : kbuf)[(bh * Nseq + n) * HDim + cd] = (__bf16)v;
                }
            }
        }
    }
}

// ---------------- kernel 3: flash attention (R12 champion, exact revert) ------------
// Swapped QK^T + pi' in-register P, double-buffered K/V, unconditional prefetch,
// single barrier + vmcnt(2)-equivalent drain per iter (vmcnt(0) before barrier
// drains own slices; prefetch issued after barrier), LDS 32768 B = 5 blocks/CU,
// VGPR ~52, plain __launch_bounds__(256) -- NO min-wave clamp (R13's spill lesson).
__global__ __launch_bounds__(256) void attn_kernel(const __bf16* __restrict__ qbuf,
                                                   const __bf16* __restrict__ kbuf,
                                                   const __bf16* __restrict__ vt,
                                                   float* __restrict__ out) {
    __shared__ __align__(16) __bf16 Kb[2][64 * 64];    // [buf][key][dim], swizzled chunks
    __shared__ __align__(16) __bf16 Vb[2][64 * 64];    // [buf][dim][pos], swizzled chunks
    int bh = blockIdx.x;
    int b = bh >> 4, h = bh & 15;
    int tile = 31 - blockIdx.y;                 // heavy-first (LPT)
    int wave = threadIdx.x >> 6, lane = threadIdx.x & 63;
    int col = lane & 15, quad = lane >> 4;
    int q0 = tile * 64 + wave * 16;

    const __bf16* qbase = qbuf + (size_t)bh * Nseq * HDim;
    const __bf16* kbase = kbuf + (size_t)bh * Nseq * HDim;
    const __bf16* vbase = vt + (size_t)bh * HDim * Nseq;

    bf16x8 aq0 = *reinterpret_cast<const bf16x8*>(qbase + (q0 + col) * HDim + quad * 8);
    bf16x8 aq1 = *reinterpret_cast<const bf16x8*>(qbase + (q0 + col) * HDim + quad * 8 + 32);

    const bf16x8 vone = {(__bf16)1.f, (__bf16)1.f, (__bf16)1.f, (__bf16)1.f,
                         (__bf16)1.f, (__bf16)1.f, (__bf16)1.f, (__bf16)1.f};

    f32x4 o[4] = {};
    f32x4 ls = {};                       // per-row denominator accumulator

    int mb = tile * 64;                 // the one masked 64-key block (last iteration)
    int loop_end = mb + 64;
    int qi = q0 + col;                  // this lane's q-row (swapped layout)

    // staging indices: 4 waves x 2 instrs cover 64 rows; 16B chunk per lane
    int rl = lane >> 3;
    int srow0 = wave * 16 + rl;                       // instr 0 rows
    int srow1 = wave * 16 + 8 + rl;                   // instr 1 rows (same row&7 = rl)
    int sc = (lane & 7) ^ rl;                         // swizzled 16B chunk
    const __bf16* ksrc0 = kbase + srow0 * HDim + sc * 8;
    const __bf16* ksrc1 = kbase + srow1 * HDim + sc * 8;
    const __bf16* vsrc0 = vbase + (size_t)srow0 * Nseq + sc * 8;
    const __bf16* vsrc1 = vbase + (size_t)srow1 * Nseq + sc * 8;
    int d0 = wave * 1024, d1 = wave * 1024 + 512;     // wave-uniform LDS dests

    // readback swizzle offsets (K/V tiles)
    int sw0 = ((quad ^ (col & 7)) * 8);
    int sw1 = (((quad + 4) ^ (col & 7)) * 8);

    // prologue: stage block 0 into buffer 0
    load_lds16(ksrc0, &Kb[0][d0]);
    load_lds16(ksrc1, &Kb[0][d1]);
    load_lds16(vsrc0, &Vb[0][d0]);
    load_lds16(vsrc1, &Vb[0][d1]);
    FENCE;

    int s = 0;
    for (int kb = 0; kb < loop_end; kb += 64) {
        asm volatile("s_waitcnt vmcnt(0)" ::: "memory");  // drain buffer s's loads
        BARRIER;                                          // staging visible to all waves
        int nkb = kb + 64;
        // unconditional prefetch into the other buffer (tail reads are mapped-safe)
        load_lds16(ksrc0 + nkb * HDim, &Kb[s ^ 1][d0]);
        load_lds16(ksrc1 + nkb * HDim, &Kb[s ^ 1][d1]);
        load_lds16(vsrc0 + nkb, &Vb[s ^ 1][d0]);
        load_lds16(vsrc1 + nkb, &Vb[s ^ 1][d1]);

        bool masked = (kb == mb);
        const __bf16* Kcur = Kb[s];
        const __bf16* Vcur = Vb[s];
        // swapped QK^T: S^T = K x Q^T -> lane: q = col, key = quad*4+r (+16g)
        f32x4 z = {};
        f32x4 sc4[4];
#pragma unroll
        for (int g = 0; g < 4; g++) {
            const __bf16* krow = Kcur + (col + 16 * g) * 64;
            bf16x8 k0 = *reinterpret_cast<const bf16x8*>(krow + sw0);
            bf16x8 k1 = *reinterpret_cast<const bf16x8*>(krow + sw1);
            sc4[g] = MFMA16(k0, aq0, z);
            sc4[g] = MFMA16(k1, aq1, sc4[g]);
        }
        // softmax (no-max): pack P directly into PV A-fragments.
        // slot j=(g&1)*4+r of fragment (g>>1) <-> V position (g>>1)*32+quad*8+(g&1)*4+r
        bf16x8 pa0, pa1;
        if (masked) {
#pragma unroll
            for (int g = 0; g < 4; g++)
#pragma unroll
                for (int r = 0; r < 4; r++) {
                    int key = kb + 16 * g + quad * 4 + r;
                    float p = (key <= qi) ? exp2f(sc4[g][r]) : 0.f;
                    if (g < 2) pa0[(g & 1) * 4 + r] = (__bf16)p;
                    else       pa1[(g & 1) * 4 + r] = (__bf16)p;
                }
        } else {
#pragma unroll
            for (int g = 0; g < 4; g++)
#pragma unroll
                for (int r = 0; r < 4; r++) {
                    float p = exp2f(sc4[g][r]);
                    if (g < 2) pa0[(g & 1) * 4 + r] = (__bf16)p;
                    else       pa1[(g & 1) * 4 + r] = (__bf16)p;
                }
        }
        // denominator: ones-MFMA row-sum (accumulates across blocks)
        ls = MFMA16(pa0, vone, ls);
        ls = MFMA16(pa1, vone, ls);
        // PV from LDS V tile (position space)
#pragma unroll
        for (int nt = 0; nt < 4; nt++) {
            const __bf16* vrow = Vcur + (col + 16 * nt) * 64;
            bf16x8 v0 = *reinterpret_cast<const bf16x8*>(vrow + sw0);
            bf16x8 v1 = *reinterpret_cast<const bf16x8*>(vrow + sw1);
            o[nt] = MFMA16(pa0, v0, o[nt]);
            o[nt] = MFMA16(pa1, v1, o[nt]);
        }
        s ^= 1;
    }

    float linv[4];
#pragma unroll
    for (int r = 0; r < 4; r++) linv[r] = 1.f / ls[r];
#pragma unroll
    for (int nt = 0; nt < 4; nt++) {
#pragma unroll
        for (int r = 0; r < 4; r++) {
            int qr = q0 + quad * 4 + r;
            out[((size_t)(b * Nseq + qr)) * Dm + h * HDim + nt * 16 + col] = o[nt][r] * linv[r];
        }
    }
}

extern "C" void kernel_launch(void* const* d_in, const int* in_sizes, int n_in,
                              void* d_out, int out_size, void* d_ws, size_t ws_size,
                              hipStream_t stream) {
    const float* x = nullptr;
    const float* w = nullptr;
    const float* bias = nullptr;
    for (int i = 0; i < n_in; i++) {
        if (in_sizes[i] == Mrows * Dm) x = (const float*)d_in[i];
        else if (in_sizes[i] == Hh * Dm * F3) w = (const float*)d_in[i];
        else if (in_sizes[i] == Hh * F3) bias = (const float*)d_in[i];
    }
    float* outp = (float*)d_out;

    // ws: wt 6 MB | kbuf 8 | qbuf 8 | vt 8 | xb 8 -> 38 MB
    char* ws = (char*)d_ws;
    __bf16* wt = (__bf16*)(ws);
    __bf16* kbuf = (__bf16*)(ws + 6291456);
    __bf16* qbuf = (__bf16*)(ws + 6291456 + 8388608);
    __bf16* vt = (__bf16*)(ws + 6291456 + 2 * 8388608);
    __bf16* xb = (__bf16*)(ws + 6291456 + 3 * 8388608);

    if (ws_size >= (size_t)(6291456 + 4 * 8388608)) {
        conv_xw_kernel<<<3584, 256, 0, stream>>>(x, xb, w, wt);
        gemm_proj<<<dim3((Mrows / 128) * (NC / 192)), 512, 0, stream>>>(xb, wt, bias, kbuf, qbuf, vt);
    } else {
        conv_w_kernel<<<dim3(Dm / 32, F3 / 64, Hh), 256, 0, stream>>>(w, wt);
        proj_small<<<dim3(Mrows / 128, Hh), 256, 0, stream>>>(x, wt, bias, kbuf, qbuf, vt);
    }
    attn_kernel<<<dim3(32, 32), 256, 0, stream>>>(qbuf, kbuf, vt, outp);
}